// Round 4
// baseline (1148.771 us; speedup 1.0000x reference)
//
#include <hip/hip_runtime.h>

#define DIM 64
#define PRESERVE 0.1f
#define P_BLK 1024    // producer blocks in count/scatter phases
#define BSH 6         // bucket = col >> 6  (64 nodes per bucket)
#define BNODES 64
#define NBMAX 2048    // max buckets (N <= 131072)
#define ROWB 20       // row packed in low 20 bits, c_local in bits [20..25]
#define ROWM ((1 << ROWB) - 1)

typedef unsigned short bf16_t;

__device__ __forceinline__ float readlane_f(float v, int l) {
    return __int_as_float(__builtin_amdgcn_readlane(__float_as_int(v), l));
}
__device__ __forceinline__ float bf2f(bf16_t u) {
    return __uint_as_float(((unsigned)u) << 16);
}
__device__ __forceinline__ bf16_t f2bf(float f) {
    unsigned u = __float_as_uint(f);
    unsigned r = (u + 0x7FFFu + ((u >> 16) & 1u)) >> 16;  // RNE
    return (bf16_t)r;
}

// ============ atomic-free CSR-lite build: one-level bucket group ============
// bucket = col >> 6. Edges get grouped by bucket (NOT fully sorted by node);
// the gather kernel holds per-node fp32 accumulators in LDS, so bucket
// granularity is all we need. Zero global atomics anywhere.

// ---- phase 1: per-(block, bucket) counts; bh[blk][bucket] coalesced ----
__global__ __launch_bounds__(256) void k_bcount(const int* __restrict__ col,
                                                int* __restrict__ bh,
                                                int E, int nb, int chunk) {
    __shared__ int hist[NBMAX];
    int t = threadIdx.x;
    for (int i = t; i < nb; i += 256) hist[i] = 0;
    __syncthreads();
    int beg = blockIdx.x * chunk;
    int end = beg + chunk;
    if (end > E) end = E;
    for (int i = beg + t; i < end; i += 256) atomicAdd(&hist[col[i] >> BSH], 1);
    __syncthreads();
    size_t base = (size_t)blockIdx.x * nb;
    for (int i = t; i < nb; i += 256) bh[base + i] = hist[i];
}

// ---- phase 2a: per-bucket exclusive scan across the P_BLK blocks ----
// grid = nb; 256 threads x 4 serial. Reads bh[blk][bucket] (strided, clean
// read-shared lines), writes bh2[bucket][blk] (coalesced).
__global__ __launch_bounds__(256) void k_bscan1(const int* __restrict__ bh,
                                                int* __restrict__ bh2,
                                                int* __restrict__ btot, int nb) {
    __shared__ int s[256];
    int t = threadIdx.x;
    int i = blockIdx.x;
    int v0 = bh[(size_t)(t * 4 + 0) * nb + i];
    int v1 = bh[(size_t)(t * 4 + 1) * nb + i];
    int v2 = bh[(size_t)(t * 4 + 2) * nb + i];
    int v3 = bh[(size_t)(t * 4 + 3) * nb + i];
    int sum = v0 + v1 + v2 + v3;
    s[t] = sum;
    __syncthreads();
    for (int off = 1; off < 256; off <<= 1) {
        int x = (t >= off) ? s[t - off] : 0;
        __syncthreads();
        s[t] += x;
        __syncthreads();
    }
    int run = s[t] - sum;  // exclusive
    size_t ob = (size_t)i * P_BLK + t * 4;
    bh2[ob + 0] = run; run += v0;
    bh2[ob + 1] = run; run += v1;
    bh2[ob + 2] = run; run += v2;
    bh2[ob + 3] = run;
    if (t == 255) btot[i] = s[255];
}

// ---- phase 2b: exclusive scan of bucket totals -> bucket bases ----
__global__ __launch_bounds__(1024) void k_bscan2(const int* __restrict__ btot,
                                                 int* __restrict__ bbase,
                                                 int nb, int E) {
    __shared__ int s[1024];
    int t = threadIdx.x;
    int a0 = (2 * t < nb) ? btot[2 * t] : 0;
    int a1 = (2 * t + 1 < nb) ? btot[2 * t + 1] : 0;
    int sum = a0 + a1;
    s[t] = sum;
    __syncthreads();
    for (int off = 1; off < 1024; off <<= 1) {
        int x = (t >= off) ? s[t - off] : 0;
        __syncthreads();
        s[t] += x;
        __syncthreads();
    }
    int excl = s[t] - sum;
    if (2 * t < nb) bbase[2 * t] = excl;
    if (2 * t + 1 < nb) bbase[2 * t + 1] = excl + a0;
    if (t == 0) bbase[nb] = E;
}

// ---- phase 3: scatter edges into bucket-grouped array (packed payload) ----
__global__ __launch_bounds__(256) void k_bscatter(
        const int* __restrict__ row, const int* __restrict__ col,
        const float* __restrict__ ew, const int* __restrict__ bh2,
        const int* __restrict__ bbase, int2* __restrict__ sered,
        int E, int nb, int chunk) {
    __shared__ int cur[NBMAX];
    int t = threadIdx.x;
    int blk = blockIdx.x;
    for (int i = t; i < nb; i += 256)
        cur[i] = bbase[i] + bh2[(size_t)i * P_BLK + blk];
    __syncthreads();
    int beg = blk * chunk;
    int end = beg + chunk;
    if (end > E) end = E;
    for (int i = beg + t; i < end; i += 256) {
        int c = col[i];
        int r = row[i];
        float w = ew[i];
        int slot = atomicAdd(&cur[c >> BSH], 1);  // LDS atomic
        int2 p;
        p.x = r | ((c & (BNODES - 1)) << ROWB);
        p.y = __float_as_int(w);
        sered[slot] = p;
    }
}

// ---- dinv: block per bucket, LDS float accum ----
__global__ __launch_bounds__(256) void k_bdeg(const int2* __restrict__ sered,
                                              const int* __restrict__ bbase,
                                              float* __restrict__ dinv, int N) {
    __shared__ float deg[BNODES];
    int t = threadIdx.x;
    int b = blockIdx.x;
    if (t < BNODES) deg[t] = 0.0f;
    __syncthreads();
    int s0 = bbase[b];
    int e0 = bbase[b + 1];
    for (int i = s0 + t; i < e0; i += 256) {
        int2 p = sered[i];
        atomicAdd(&deg[((unsigned)p.x) >> ROWB], __int_as_float(p.y));
    }
    __syncthreads();
    if (t < BNODES) {
        int node = (b << BSH) + t;
        if (node < N) dinv[node] = rsqrtf(1.0f + deg[t]);  // self-loop w=1
    }
}

// ---------- xs = bf16( (x @ W) * dinv[row] ) ----------
// Zero-LDS: lane d holds W[:,d] in 64 VGPRs; x broadcast via v_readlane.
__global__ __launch_bounds__(256) void k_mm(
        const float* __restrict__ x, const float* __restrict__ W,
        const float* __restrict__ dinv, bf16_t* __restrict__ xs, int n) {
    int tid = threadIdx.x;
    int lane = tid & 63;
    int waveId = blockIdx.x * 4 + (tid >> 6);
    int nWaves = gridDim.x * 4;

    float Wr[DIM];
#pragma unroll
    for (int k = 0; k < DIM; ++k) Wr[k] = W[k * DIM + lane];

    for (int r0 = waveId * 4; r0 < n; r0 += nWaves * 4) {
        if (r0 + 3 < n) {
            float x0 = x[(size_t)(r0 + 0) * DIM + lane];
            float x1 = x[(size_t)(r0 + 1) * DIM + lane];
            float x2 = x[(size_t)(r0 + 2) * DIM + lane];
            float x3 = x[(size_t)(r0 + 3) * DIM + lane];
            float a0 = 0.f, a1 = 0.f, a2 = 0.f, a3 = 0.f;
#pragma unroll
            for (int k = 0; k < DIM; ++k) {
                float w = Wr[k];
                a0 += readlane_f(x0, k) * w;
                a1 += readlane_f(x1, k) * w;
                a2 += readlane_f(x2, k) * w;
                a3 += readlane_f(x3, k) * w;
            }
            xs[(size_t)(r0 + 0) * DIM + lane] = f2bf(a0 * dinv[r0 + 0]);
            xs[(size_t)(r0 + 1) * DIM + lane] = f2bf(a1 * dinv[r0 + 1]);
            xs[(size_t)(r0 + 2) * DIM + lane] = f2bf(a2 * dinv[r0 + 2]);
            xs[(size_t)(r0 + 3) * DIM + lane] = f2bf(a3 * dinv[r0 + 3]);
        } else {
            for (int r = r0; r < n; ++r) {
                float xv = x[(size_t)r * DIM + lane];
                float a = 0.f;
#pragma unroll
                for (int k = 0; k < DIM; ++k) a += readlane_f(xv, k) * Wr[k];
                xs[(size_t)r * DIM + lane] = f2bf(a * dinv[r]);
            }
        }
    }
}

// ---------- fused gather: block per bucket, 64x64 fp32 accumulators in LDS ----
// acc[cl][lane] starts as xs[self]; every edge does a coalesced 128B row load
// of xs[row] and a fire-and-forget ds_add_f32 -> no serial FMA chain, deep MLP.
__global__ __launch_bounds__(256) void k_bgather(
        const bf16_t* __restrict__ xs, const int2* __restrict__ sered,
        const int* __restrict__ bbase, const float* __restrict__ dinv,
        const float* __restrict__ bias, const float* __restrict__ xprev,
        float* __restrict__ out, int N) {
    __shared__ float acc[BNODES * DIM];
    int t = threadIdx.x;
    int lane = t & 63;
    int wid = t >> 6;
    int b = blockIdx.x;
    int nbase = b << BSH;

    // init: self term (xs already contains dinv[row] factor)
    for (int i = wid; i < BNODES; i += 4) {
        int node = nbase + i;
        acc[i * DIM + lane] = (node < N) ? bf2f(xs[(size_t)node * DIM + lane]) : 0.0f;
    }
    __syncthreads();

    int s0 = bbase[b];
    int e0 = bbase[b + 1];
    for (int b0 = s0 + wid * 64; b0 < e0; b0 += 256) {
        int m = e0 - b0;
        if (m > 64) m = 64;
        int kl = 0, wl = 0;
        if (lane < m) {
            int2 p = sered[b0 + lane];  // coalesced batch load
            kl = p.x;
            wl = p.y;
        }
        int j = 0;
        for (; j + 3 < m; j += 4) {
            int k0 = __builtin_amdgcn_readlane(kl, j);
            int k1 = __builtin_amdgcn_readlane(kl, j + 1);
            int k2 = __builtin_amdgcn_readlane(kl, j + 2);
            int k3 = __builtin_amdgcn_readlane(kl, j + 3);
            float w0 = readlane_f(__int_as_float(wl), j);
            float w1 = readlane_f(__int_as_float(wl), j + 1);
            float w2 = readlane_f(__int_as_float(wl), j + 2);
            float w3 = readlane_f(__int_as_float(wl), j + 3);
            float a0 = bf2f(xs[(size_t)(k0 & ROWM) * DIM + lane]);
            float a1 = bf2f(xs[(size_t)(k1 & ROWM) * DIM + lane]);
            float a2 = bf2f(xs[(size_t)(k2 & ROWM) * DIM + lane]);
            float a3 = bf2f(xs[(size_t)(k3 & ROWM) * DIM + lane]);
            atomicAdd(&acc[(((unsigned)k0) >> ROWB) * DIM + lane], a0 * w0);
            atomicAdd(&acc[(((unsigned)k1) >> ROWB) * DIM + lane], a1 * w1);
            atomicAdd(&acc[(((unsigned)k2) >> ROWB) * DIM + lane], a2 * w2);
            atomicAdd(&acc[(((unsigned)k3) >> ROWB) * DIM + lane], a3 * w3);
        }
        for (; j < m; ++j) {
            int k0 = __builtin_amdgcn_readlane(kl, j);
            float w0 = readlane_f(__int_as_float(wl), j);
            float a0 = bf2f(xs[(size_t)(k0 & ROWM) * DIM + lane]);
            atomicAdd(&acc[(((unsigned)k0) >> ROWB) * DIM + lane], a0 * w0);
        }
    }
    __syncthreads();

    float bl = bias[lane];
    for (int i = wid; i < BNODES; i += 4) {
        int node = nbase + i;
        if (node < N) {
            float v = (1.0f - PRESERVE) * (acc[i * DIM + lane] * dinv[node] + bl)
                    + PRESERVE * xprev[(size_t)node * DIM + lane];
            out[(size_t)node * DIM + lane] = v;
        }
    }
}

extern "C" void kernel_launch(void* const* d_in, const int* in_sizes, int n_in,
                              void* d_out, int out_size, void* d_ws, size_t ws_size,
                              hipStream_t stream) {
    const float* x  = (const float*)d_in[0];
    const int*   ei = (const int*)d_in[1];
    const float* ew = (const float*)d_in[2];
    const float* W1 = (const float*)d_in[3];
    const float* b1 = (const float*)d_in[4];
    const float* W2 = (const float*)d_in[5];
    const float* b2 = (const float*)d_in[6];

    const int N = in_sizes[0] / DIM;      // 100000
    const int E = in_sizes[2];            // 1250000
    const int* row = ei;
    const int* col = ei + E;

    const int nb = (N + BNODES - 1) >> BSH;         // 1563 buckets
    const int chunk = (E + P_BLK - 1) / P_BLK;

    // workspace layout; bh/bh2 alias temp (dead until bgather-1 writes it,
    // strictly after bscatter's last read of bh2 in stream order)
    int2* sered   = (int2*)d_ws;                          // E
    float* dinv   = (float*)(sered + E);                  // N
    bf16_t* xs    = (bf16_t*)(dinv + N);                  // N*DIM bf16
    int* btot     = (int*)(xs + (size_t)N * DIM);         // nb
    int* bbase    = btot + nb;                            // nb+1
    float* temp   = (float*)(bbase + nb + 1);             // N*DIM fp32
    int* bh       = (int*)temp;                           //   alias: P_BLK*nb
    int* bh2      = bh + (size_t)P_BLK * nb;              //   alias: nb*P_BLK

    const int B = 256;
    const int nblkMM = 1024;             // grid-stride; 4096 waves

    // ---- build (zero global atomics) ----
    k_bcount<<<P_BLK, B, 0, stream>>>(col, bh, E, nb, chunk);
    k_bscan1<<<nb, B, 0, stream>>>(bh, bh2, btot, nb);
    k_bscan2<<<1, 1024, 0, stream>>>(btot, bbase, nb, E);
    k_bscatter<<<P_BLK, B, 0, stream>>>(row, col, ew, bh2, bbase, sered, E, nb, chunk);
    k_bdeg<<<nb, B, 0, stream>>>(sered, bbase, dinv, N);

    // ---- layer 1 ----
    k_mm<<<nblkMM, B, 0, stream>>>(x, W1, dinv, xs, N);
    k_bgather<<<nb, B, 0, stream>>>(xs, sered, bbase, dinv, b1, x, temp, N);

    // ---- layer 2 ----
    k_mm<<<nblkMM, B, 0, stream>>>(temp, W2, dinv, xs, N);
    k_bgather<<<nb, B, 0, stream>>>(xs, sered, bbase, dinv, b2, temp, (float*)d_out, N);
}

// Round 6
// 273.826 us; speedup vs baseline: 4.1953x; 4.1953x over previous
//
#include <hip/hip_runtime.h>

#define DIM 64
#define PRESERVE 0.1f
#define P_BLK 1024    // producer blocks in count/scatter phases
#define BSH 7         // bucket = col >> 7 (128 nodes per bucket)
#define BNODES 128
#define NBMAX 1024    // max buckets (N <= 131072)
#define ROWB 20       // row in low 20 bits, c_local in bits [20..26]
#define ROWM ((1 << ROWB) - 1)

static_assert(BNODES == (1 << BSH), "bucket geometry");
static_assert((1 << ROWB) >= 131072, "row must fit in ROWB bits for N<=131072");

typedef unsigned short bf16_t;

__device__ __forceinline__ float readlane_f(float v, int l) {
    return __int_as_float(__builtin_amdgcn_readlane(__float_as_int(v), l));
}
__device__ __forceinline__ float bf2f(bf16_t u) {
    return __uint_as_float(((unsigned)u) << 16);
}
__device__ __forceinline__ bf16_t f2bf(float f) {
    unsigned u = __float_as_uint(f);
    unsigned r = (u + 0x7FFFu + ((u >> 16) & 1u)) >> 16;  // RNE
    return (bf16_t)r;
}

// ============ atomic-free CSR build: two-level bucket sort ============
// bucket = col >> 7. LDS atomics only; every block owns a deterministic
// exclusive slot range per bucket -> zero global atomics anywhere.

// ---- phase 1: per-(block, bucket) counts; bh[blk][bucket] coalesced ----
__global__ __launch_bounds__(256) void k_bcount(const int* __restrict__ col,
                                                int* __restrict__ bh,
                                                int E, int nb, int chunk) {
    __shared__ int hist[NBMAX];
    int t = threadIdx.x;
    for (int i = t; i < nb; i += 256) hist[i] = 0;
    __syncthreads();
    int beg = blockIdx.x * chunk;
    int end = beg + chunk;
    if (end > E) end = E;
    for (int i = beg + t; i < end; i += 256) atomicAdd(&hist[col[i] >> BSH], 1);
    __syncthreads();
    size_t base = (size_t)blockIdx.x * nb;
    for (int i = t; i < nb; i += 256) bh[base + i] = hist[i];
}

// ---- phase 2a: per-bucket exclusive scan across the P_BLK blocks ----
// grid = nb; 256 threads x 4 serial. Reads bh column-wise (L2 absorbs the
// 3.2MB matrix), writes bh2[bucket][blk] coalesced.
__global__ __launch_bounds__(256) void k_bscan1(const int* __restrict__ bh,
                                                int* __restrict__ bh2,
                                                int* __restrict__ btot, int nb) {
    __shared__ int s[256];
    int t = threadIdx.x;
    int i = blockIdx.x;
    int v0 = bh[(size_t)(t * 4 + 0) * nb + i];
    int v1 = bh[(size_t)(t * 4 + 1) * nb + i];
    int v2 = bh[(size_t)(t * 4 + 2) * nb + i];
    int v3 = bh[(size_t)(t * 4 + 3) * nb + i];
    int sum = v0 + v1 + v2 + v3;
    s[t] = sum;
    __syncthreads();
    for (int off = 1; off < 256; off <<= 1) {
        int x = (t >= off) ? s[t - off] : 0;
        __syncthreads();
        s[t] += x;
        __syncthreads();
    }
    int run = s[t] - sum;  // exclusive
    size_t ob = (size_t)i * P_BLK + t * 4;
    bh2[ob + 0] = run; run += v0;
    bh2[ob + 1] = run; run += v1;
    bh2[ob + 2] = run; run += v2;
    bh2[ob + 3] = run;
    if (t == 255) btot[i] = s[255];
}

// ---- phase 2b: exclusive scan of bucket totals -> bucket bases ----
__global__ __launch_bounds__(1024) void k_bscan2(const int* __restrict__ btot,
                                                 int* __restrict__ bbase,
                                                 int nb, int E) {
    __shared__ int s[1024];
    int t = threadIdx.x;
    int v = (t < nb) ? btot[t] : 0;
    s[t] = v;
    __syncthreads();
    for (int off = 1; off < 1024; off <<= 1) {
        int x = (t >= off) ? s[t - off] : 0;
        __syncthreads();
        s[t] += x;
        __syncthreads();
    }
    if (t < nb) bbase[t] = s[t] - v;  // exclusive
    if (t == 0) bbase[nb] = E;
}

// ---- phase 3: scatter edges into bucket-grouped array (packed payload) ----
__global__ __launch_bounds__(256) void k_bscatter(
        const int* __restrict__ row, const int* __restrict__ col,
        const float* __restrict__ ew, const int* __restrict__ bh2,
        const int* __restrict__ bbase, int2* __restrict__ sered,
        int E, int nb, int chunk) {
    __shared__ int cur[NBMAX];
    int t = threadIdx.x;
    int blk = blockIdx.x;
    for (int i = t; i < nb; i += 256)
        cur[i] = bbase[i] + bh2[(size_t)i * P_BLK + blk];
    __syncthreads();
    int beg = blk * chunk;
    int end = beg + chunk;
    if (end > E) end = E;
    for (int i = beg + t; i < end; i += 256) {
        int c = col[i];
        int r = row[i];
        float w = ew[i];
        int slot = atomicAdd(&cur[c >> BSH], 1);  // LDS atomic
        int2 p;
        p.x = r | ((c & (BNODES - 1)) << ROWB);
        p.y = __float_as_int(w);
        sered[slot] = p;
    }
}

// ---- phase 4: per-bucket local CSR + offsets + dinv (fused degree pass) ----
__global__ __launch_bounds__(256) void k_bcsr(
        const int2* __restrict__ sered, const int* __restrict__ bbase,
        int2* __restrict__ sedge, int* __restrict__ offsets,
        float* __restrict__ dinv, int N, int E) {
    __shared__ int cnt[BNODES];
    __shared__ float degw[BNODES];
    __shared__ int sc[BNODES];
    __shared__ int cur[BNODES];
    int t = threadIdx.x;
    int b = blockIdx.x;
    if (t < BNODES) { cnt[t] = 0; degw[t] = 0.0f; }
    __syncthreads();
    int s0 = bbase[b];
    int e0 = bbase[b + 1];
    for (int i = s0 + t; i < e0; i += 256) {
        int2 p = sered[i];
        int loc = ((unsigned)p.x) >> ROWB;
        atomicAdd(&cnt[loc], 1);
        atomicAdd(&degw[loc], __int_as_float(p.y));
    }
    __syncthreads();
    if (t < BNODES) sc[t] = cnt[t];
    __syncthreads();
    for (int off = 1; off < BNODES; off <<= 1) {
        int x = 0;
        if (t < BNODES && t >= off) x = sc[t - off];
        __syncthreads();
        if (t < BNODES) sc[t] += x;
        __syncthreads();
    }
    if (t < BNODES) {
        int excl = sc[t] - cnt[t];
        cur[t] = excl;
        int node = (b << BSH) + t;
        if (node < N) {
            offsets[node] = s0 + excl;
            dinv[node] = rsqrtf(1.0f + degw[t]);  // self-loop w=1, deg >= 1
        }
    }
    if (b == 0 && t == 0) offsets[N] = E;
    __syncthreads();
    for (int i = s0 + t; i < e0; i += 256) {
        int2 p = sered[i];
        int loc = ((unsigned)p.x) >> ROWB;
        int slot = atomicAdd(&cur[loc], 1);  // LDS atomic
        int2 q;
        q.x = p.x & ROWM;  // clean row for the gather
        q.y = p.y;
        sedge[s0 + slot] = q;
    }
}

// ---------- xs = bf16( (x @ W) * dinv[row] ) ----------
// Zero-LDS: lane d holds W[:,d] in 64 VGPRs; x broadcast via v_readlane.
__global__ __launch_bounds__(256) void k_mm(
        const float* __restrict__ x, const float* __restrict__ W,
        const float* __restrict__ dinv, bf16_t* __restrict__ xs, int n) {
    int tid = threadIdx.x;
    int lane = tid & 63;
    int waveId = blockIdx.x * 4 + (tid >> 6);
    int nWaves = gridDim.x * 4;

    float Wr[DIM];
#pragma unroll
    for (int k = 0; k < DIM; ++k) Wr[k] = W[k * DIM + lane];

    for (int r0 = waveId * 4; r0 < n; r0 += nWaves * 4) {
        if (r0 + 3 < n) {
            float x0 = x[(size_t)(r0 + 0) * DIM + lane];
            float x1 = x[(size_t)(r0 + 1) * DIM + lane];
            float x2 = x[(size_t)(r0 + 2) * DIM + lane];
            float x3 = x[(size_t)(r0 + 3) * DIM + lane];
            float a0 = 0.f, a1 = 0.f, a2 = 0.f, a3 = 0.f;
#pragma unroll
            for (int k = 0; k < DIM; ++k) {
                float w = Wr[k];
                a0 += readlane_f(x0, k) * w;
                a1 += readlane_f(x1, k) * w;
                a2 += readlane_f(x2, k) * w;
                a3 += readlane_f(x3, k) * w;
            }
            xs[(size_t)(r0 + 0) * DIM + lane] = f2bf(a0 * dinv[r0 + 0]);
            xs[(size_t)(r0 + 1) * DIM + lane] = f2bf(a1 * dinv[r0 + 1]);
            xs[(size_t)(r0 + 2) * DIM + lane] = f2bf(a2 * dinv[r0 + 2]);
            xs[(size_t)(r0 + 3) * DIM + lane] = f2bf(a3 * dinv[r0 + 3]);
        } else {
            for (int r = r0; r < n; ++r) {
                float xv = x[(size_t)r * DIM + lane];
                float a = 0.f;
#pragma unroll
                for (int k = 0; k < DIM; ++k) a += readlane_f(xv, k) * Wr[k];
                xs[(size_t)r * DIM + lane] = f2bf(a * dinv[r]);
            }
        }
    }
}

// ---------- gather (wave per node, lane = dim), 8 loads in flight ----------
// out[c] = 0.9*( dinv[c]*( xs[c] + sum_e w_e*xs[row_e] ) + b ) + 0.1*xprev[c]
__global__ __launch_bounds__(256) void k_gather(
        const bf16_t* __restrict__ xs, const int* __restrict__ offsets,
        const int2* __restrict__ sedge, const float* __restrict__ dinv,
        const float* __restrict__ b, const float* __restrict__ xprev,
        float* __restrict__ out, int n) {
    int tid = threadIdx.x;
    int lane = tid & 63;
    int c = blockIdx.x * 4 + (tid >> 6);
    if (c >= n) return;
    float di = dinv[c];
    float xp = xprev[(size_t)c * DIM + lane];  // issue early
    float bl = b[lane];
    float acc0 = bf2f(xs[(size_t)c * DIM + lane]);
    float acc1 = 0.0f;
    int beg = offsets[c];
    int end = offsets[c + 1];
    for (int b0 = beg; b0 < end; b0 += 64) {
        int m = end - b0;
        if (m > 64) m = 64;
        int r_l = 0, w_l = 0;
        if (lane < m) {
            int2 p = sedge[b0 + lane];  // coalesced batch load
            r_l = p.x;
            w_l = p.y;
        }
        int j = 0;
        for (; j + 7 < m; j += 8) {
            int k0 = __builtin_amdgcn_readlane(r_l, j);
            int k1 = __builtin_amdgcn_readlane(r_l, j + 1);
            int k2 = __builtin_amdgcn_readlane(r_l, j + 2);
            int k3 = __builtin_amdgcn_readlane(r_l, j + 3);
            int k4 = __builtin_amdgcn_readlane(r_l, j + 4);
            int k5 = __builtin_amdgcn_readlane(r_l, j + 5);
            int k6 = __builtin_amdgcn_readlane(r_l, j + 6);
            int k7 = __builtin_amdgcn_readlane(r_l, j + 7);
            float w0 = readlane_f(__int_as_float(w_l), j);
            float w1 = readlane_f(__int_as_float(w_l), j + 1);
            float w2 = readlane_f(__int_as_float(w_l), j + 2);
            float w3 = readlane_f(__int_as_float(w_l), j + 3);
            float w4 = readlane_f(__int_as_float(w_l), j + 4);
            float w5 = readlane_f(__int_as_float(w_l), j + 5);
            float w6 = readlane_f(__int_as_float(w_l), j + 6);
            float w7 = readlane_f(__int_as_float(w_l), j + 7);
            float a0 = bf2f(xs[(size_t)k0 * DIM + lane]);
            float a1 = bf2f(xs[(size_t)k1 * DIM + lane]);
            float a2 = bf2f(xs[(size_t)k2 * DIM + lane]);
            float a3 = bf2f(xs[(size_t)k3 * DIM + lane]);
            float a4 = bf2f(xs[(size_t)k4 * DIM + lane]);
            float a5 = bf2f(xs[(size_t)k5 * DIM + lane]);
            float a6 = bf2f(xs[(size_t)k6 * DIM + lane]);
            float a7 = bf2f(xs[(size_t)k7 * DIM + lane]);
            acc0 += a0 * w0;
            acc1 += a1 * w1;
            acc0 += a2 * w2;
            acc1 += a3 * w3;
            acc0 += a4 * w4;
            acc1 += a5 * w5;
            acc0 += a6 * w6;
            acc1 += a7 * w7;
        }
        for (; j + 3 < m; j += 4) {
            int k0 = __builtin_amdgcn_readlane(r_l, j);
            int k1 = __builtin_amdgcn_readlane(r_l, j + 1);
            int k2 = __builtin_amdgcn_readlane(r_l, j + 2);
            int k3 = __builtin_amdgcn_readlane(r_l, j + 3);
            float w0 = readlane_f(__int_as_float(w_l), j);
            float w1 = readlane_f(__int_as_float(w_l), j + 1);
            float w2 = readlane_f(__int_as_float(w_l), j + 2);
            float w3 = readlane_f(__int_as_float(w_l), j + 3);
            float a0 = bf2f(xs[(size_t)k0 * DIM + lane]);
            float a1 = bf2f(xs[(size_t)k1 * DIM + lane]);
            float a2 = bf2f(xs[(size_t)k2 * DIM + lane]);
            float a3 = bf2f(xs[(size_t)k3 * DIM + lane]);
            acc0 += a0 * w0;
            acc1 += a1 * w1;
            acc0 += a2 * w2;
            acc1 += a3 * w3;
        }
        for (; j < m; ++j) {
            int k0 = __builtin_amdgcn_readlane(r_l, j);
            float w0 = readlane_f(__int_as_float(w_l), j);
            acc0 += bf2f(xs[(size_t)k0 * DIM + lane]) * w0;
        }
    }
    float acc = acc0 + acc1;
    float v = (1.0f - PRESERVE) * (acc * di + bl) + PRESERVE * xp;
    out[(size_t)c * DIM + lane] = v;
}

extern "C" void kernel_launch(void* const* d_in, const int* in_sizes, int n_in,
                              void* d_out, int out_size, void* d_ws, size_t ws_size,
                              hipStream_t stream) {
    const float* x  = (const float*)d_in[0];
    const int*   ei = (const int*)d_in[1];
    const float* ew = (const float*)d_in[2];
    const float* W1 = (const float*)d_in[3];
    const float* b1 = (const float*)d_in[4];
    const float* W2 = (const float*)d_in[5];
    const float* b2 = (const float*)d_in[6];

    const int N = in_sizes[0] / DIM;      // 100000
    const int E = in_sizes[2];            // 1250000
    const int* row = ei;
    const int* col = ei + E;

    const int nb = (N + BNODES - 1) >> BSH;         // 782 buckets
    const int chunk = (E + P_BLK - 1) / P_BLK;

    // workspace layout; bh/bh2/sered live inside temp (all dead before
    // gather-1 writes temp; sered does not overlap bh2, which it follows)
    int2* sedge   = (int2*)d_ws;                          // E
    float* dinv   = (float*)(sedge + E);                  // N
    bf16_t* xs    = (bf16_t*)(dinv + N);                  // N*DIM bf16
    int* offsets  = (int*)(xs + (size_t)N * DIM);         // N+1
    int* btot     = offsets + N + 1;                      // nb
    int* bbase    = btot + nb;                            // nb+1
    // align temp to 256B
    size_t toff = (size_t)((char*)(bbase + nb + 1) - (char*)d_ws);
    toff = (toff + 255) & ~(size_t)255;
    float* temp   = (float*)((char*)d_ws + toff);         // N*DIM fp32
    int* bh2      = (int*)temp;                           //   alias: nb*P_BLK
    int* bh       = bh2 + (size_t)nb * P_BLK;             //   alias: P_BLK*nb
    int2* sered   = (int2*)(bh + (size_t)P_BLK * nb);     //   alias: E int2

    const int B = 256;
    const int nblkG = (N + 3) / 4;
    const int nblkMM = 1024;             // grid-stride; 4096 waves

    // ---- CSR build (zero global atomics) ----
    k_bcount<<<P_BLK, B, 0, stream>>>(col, bh, E, nb, chunk);
    k_bscan1<<<nb, B, 0, stream>>>(bh, bh2, btot, nb);
    k_bscan2<<<1, 1024, 0, stream>>>(btot, bbase, nb, E);
    k_bscatter<<<P_BLK, B, 0, stream>>>(row, col, ew, bh2, bbase, sered, E, nb, chunk);
    k_bcsr<<<nb, B, 0, stream>>>(sered, bbase, sedge, offsets, dinv, N, E);

    // ---- layer 1 ----
    k_mm<<<nblkMM, B, 0, stream>>>(x, W1, dinv, xs, N);
    k_gather<<<nblkG, B, 0, stream>>>(xs, offsets, sedge, dinv, b1, x, temp, N);

    // ---- layer 2 ----
    k_mm<<<nblkMM, B, 0, stream>>>(temp, W2, dinv, xs, N);
    k_gather<<<nblkG, B, 0, stream>>>(xs, offsets, sedge, dinv, b2, temp, (float*)d_out, N);
}